// Round 3
// baseline (686.331 us; speedup 1.0000x reference)
//
#include <hip/hip_runtime.h>
#include <stdint.h>

typedef __attribute__((ext_vector_type(8))) short bf16x8;
typedef __attribute__((ext_vector_type(4))) float f32x4;
typedef __attribute__((ext_vector_type(4))) float fl4;
typedef __attribute__((ext_vector_type(4))) unsigned short u16x4;
typedef __attribute__((ext_vector_type(8))) unsigned short u16x8;

constexpr int SEQ = 2048;
constexpr int DMODEL = 1024;
constexpr int NH = 16;
constexpr int DKH = 64;
constexpr float SEXP = 0.18033688f;  // log2(e)/8 — exp(s/8) == exp2(s*SEXP)

__device__ __forceinline__ unsigned short f2bf(float x) {
  union { float f; uint32_t u; } c;
  c.f = x;
  uint32_t u = c.u;
  u += 0x7FFFu + ((u >> 16) & 1u);
  return (unsigned short)(u >> 16);
}

__device__ __forceinline__ float bf2f(unsigned short u) {
  union { uint32_t u; float f; } c;
  c.u = ((uint32_t)u) << 16;
  return c.f;
}

__device__ __forceinline__ uint32_t cvtpk(float lo, float hi) {
  uint32_t r;
  asm("v_cvt_pk_bf16_f32 %0, %1, %2" : "=v"(r) : "v"(lo), "v"(hi));
  return r;
}

__device__ __forceinline__ int swz(int row) { return (row & 3) ^ ((row >> 2) & 3); }

__device__ __forceinline__ void gload16(const unsigned short* g, unsigned short* l) {
  __builtin_amdgcn_global_load_lds((const __attribute__((address_space(1))) void*)g,
                                   (__attribute__((address_space(3))) void*)l, 16, 0, 0);
}

// ---------------- fp32 -> bf16 conversion (query/key/value) ----------------
__global__ __launch_bounds__(256) void cvtk(
    const float* __restrict__ s0, const float* __restrict__ s1, const float* __restrict__ s2,
    unsigned short* __restrict__ d0, unsigned short* __restrict__ d1, unsigned short* __restrict__ d2) {
  const float* s = blockIdx.y == 0 ? s0 : blockIdx.y == 1 ? s1 : s2;
  unsigned short* d = blockIdx.y == 0 ? d0 : blockIdx.y == 1 ? d1 : d2;
  const size_t i = ((size_t)blockIdx.x * 256 + threadIdx.x) * 8;
  fl4 a = *(const fl4*)(s + i);
  fl4 c = *(const fl4*)(s + i + 4);
  u16x8 r;
#pragma unroll
  for (int j = 0; j < 4; ++j) { r[j] = f2bf(a[j]); r[4 + j] = f2bf(c[j]); }
  *(u16x8*)(d + i) = r;
}

// ---------------- GEMM: C[8192,1024] = A_bf16[8192,1024] * Bw_fp32[1024,1024]^T + bias ----------------
// A staged via global_load_lds (pre-swizzled source); B reg-staged fp32->bf16.
// EPI: 0 = bf16 row-major; 1 = bf16 V^T [b][h][d][s]; 2 = fp32 row-major
template <int EPI>
__global__ __launch_bounds__(256, 2) void gemm2(
    const unsigned short* __restrict__ A, const float* __restrict__ Bw,
    const float* __restrict__ bias, void* __restrict__ Cp) {
  constexpr int K = DMODEL;
  constexpr int N = DMODEL;
  __shared__ unsigned short As[128 * 32];
  __shared__ unsigned short Bs[128 * 32];
  const int tid = threadIdx.x;
  const int wave = tid >> 6, lane = tid & 63;
  const int g = lane >> 4, ln = lane & 15;
  const int o = blockIdx.x;                 // 512 blocks, XCD-chunked by output column group
  const int l = (o & 7) * 64 + (o >> 3);
  const int r0 = (l & 63) * 128, c0 = (l >> 6) * 128;
  const int wr = (wave >> 1) * 64, wc = (wave & 1) * 64;
  const int brow = tid >> 2;
  const int cc = tid & 3;

  f32x4 acc[4][4] = {};

  for (int kt = 0; kt < K; kt += 32) {
    // B fp32 loads (issued before barrier; no LDS touch)
    const size_t bo0 = (size_t)(c0 + brow) * K + kt + cc * 8;
    const size_t bo1 = (size_t)(c0 + brow + 64) * K + kt + cc * 8;
    fl4 b0 = *(const fl4*)(Bw + bo0);
    fl4 b1 = *(const fl4*)(Bw + bo0 + 4);
    fl4 b2 = *(const fl4*)(Bw + bo1);
    fl4 b3 = *(const fl4*)(Bw + bo1 + 4);
    __syncthreads();  // prior iteration's LDS reads complete
    // A -> LDS async, 16B/lane; source pre-swizzled so linear LDS holds swizzled chunks
#pragma unroll
    for (int i = 0; i < 2; ++i) {
      const int s = i * 256 + tid;
      const int row = s >> 2, c = s & 3;
      const unsigned short* src = A + (size_t)(r0 + row) * K + kt + ((c ^ swz(row)) * 8);
      gload16(src, As + (size_t)(i * 256 + wave * 64) * 8);
    }
    // B convert + LDS write (swizzled chunks)
    {
      const int ch0 = (cc ^ swz(brow)) * 8;
      const int ch1 = (cc ^ swz(brow + 64)) * 8;
      u16x4 t0, t1, t2, t3;
#pragma unroll
      for (int j = 0; j < 4; ++j) { t0[j] = f2bf(b0[j]); t1[j] = f2bf(b1[j]); t2[j] = f2bf(b2[j]); t3[j] = f2bf(b3[j]); }
      *(u16x4*)(Bs + brow * 32 + ch0) = t0;
      *(u16x4*)(Bs + brow * 32 + ch0 + 4) = t1;
      *(u16x4*)(Bs + (brow + 64) * 32 + ch1) = t2;
      *(u16x4*)(Bs + (brow + 64) * 32 + ch1 + 4) = t3;
    }
    asm volatile("s_waitcnt vmcnt(0)");
    __syncthreads();
    bf16x8 af[4], bfr[4];
#pragma unroll
    for (int m = 0; m < 4; ++m) {
      const int row = wr + m * 16 + ln;
      af[m] = *(const bf16x8*)(As + row * 32 + ((g ^ swz(row)) * 8));
    }
#pragma unroll
    for (int n = 0; n < 4; ++n) {
      const int row = wc + n * 16 + ln;
      bfr[n] = *(const bf16x8*)(Bs + row * 32 + ((g ^ swz(row)) * 8));
    }
#pragma unroll
    for (int m = 0; m < 4; ++m)
#pragma unroll
      for (int n = 0; n < 4; ++n)
        acc[m][n] = __builtin_amdgcn_mfma_f32_16x16x32_bf16(af[m], bfr[n], acc[m][n], 0, 0, 0);
  }

  // epilogue: C/D layout col = lane&15, row = (lane>>4)*4 + reg
#pragma unroll
  for (int m = 0; m < 4; ++m) {
    const int row = r0 + wr + m * 16 + g * 4;
#pragma unroll
    for (int n = 0; n < 4; ++n) {
      const int col = c0 + wc + n * 16 + ln;
      const float bv = bias[col];
      f32x4 v = acc[m][n];
      if (EPI == 2) {
        float* C = (float*)Cp;
#pragma unroll
        for (int r = 0; r < 4; ++r) C[(size_t)(row + r) * N + col] = v[r] + bv;
      } else if (EPI == 0) {
        unsigned short* C = (unsigned short*)Cp;
#pragma unroll
        for (int r = 0; r < 4; ++r) C[(size_t)(row + r) * N + col] = f2bf(v[r] + bv);
      } else {
        unsigned short* Vt = (unsigned short*)Cp;
        const int bb = row >> 11, sl = row & 2047;
        const int h = col >> 6, d = col & 63;
        u16x4 pk;
#pragma unroll
        for (int r = 0; r < 4; ++r) pk[r] = f2bf(v[r] + bv);
        *(u16x4*)(Vt + ((size_t)((bb * NH + h) * DKH + d)) * SEQ + sl) = pk;
      }
    }
  }
}

// ---------------- Kernel A: head-softmax denominators ----------------
// Per wave: q64 x kv32, loop over 16 heads; lane-local sum of exp over heads.
// XCD-chunked: each XCD sees one b's K (4MB, L2-resident) across 16 q-groups.
__global__ __launch_bounds__(256, 3) void denomk(
    const unsigned short* __restrict__ Qp, const unsigned short* __restrict__ Kp,
    unsigned short* __restrict__ rDb) {
  const int tid = threadIdx.x, wave = tid >> 6, lane = tid & 63;
  const int g = lane >> 4, ln = lane & 15;
  const int o = blockIdx.x;                  // 2048 blocks
  const int l = (o & 7) * 256 + (o >> 3);    // bijective XCD chunking
  const int b = l >> 9;
  const int qg = (l >> 4) & 31;
  const int kvg = l & 15;
  const int q0 = qg * 64, kv0 = kvg * 128 + wave * 32;

  f32x4 psum[2][4] = {};

  for (int h = 0; h < NH; ++h) {
    const int hb = h * DKH;
    bf16x8 qf[2][4];
#pragma unroll
    for (int ks = 0; ks < 2; ++ks)
#pragma unroll
      for (int n = 0; n < 4; ++n)
        qf[ks][n] = *(const bf16x8*)(Qp + (size_t)(b * SEQ + q0 + n * 16 + ln) * DMODEL + hb + ks * 32 + g * 8);
    bf16x8 kf[2][2];
#pragma unroll
    for (int m = 0; m < 2; ++m)
#pragma unroll
      for (int ks = 0; ks < 2; ++ks)
        kf[m][ks] = *(const bf16x8*)(Kp + (size_t)(b * SEQ + kv0 + m * 16 + ln) * DMODEL + hb + ks * 32 + g * 8);
    f32x4 s[2][4] = {};
#pragma unroll
    for (int m = 0; m < 2; ++m)
#pragma unroll
      for (int n = 0; n < 4; ++n) {
        s[m][n] = __builtin_amdgcn_mfma_f32_16x16x32_bf16(kf[m][0], qf[0][n], s[m][n], 0, 0, 0);
        s[m][n] = __builtin_amdgcn_mfma_f32_16x16x32_bf16(kf[m][1], qf[1][n], s[m][n], 0, 0, 0);
      }
#pragma unroll
    for (int m = 0; m < 2; ++m)
#pragma unroll
      for (int n = 0; n < 4; ++n)
#pragma unroll
        for (int r = 0; r < 4; ++r) psum[m][n][r] += exp2f(s[m][n][r] * SEXP);
  }

#pragma unroll
  for (int m = 0; m < 2; ++m)
#pragma unroll
    for (int n = 0; n < 4; ++n) {
      u16x4 st;
#pragma unroll
      for (int r = 0; r < 4; ++r) st[r] = f2bf(1.0f / psum[m][n][r]);
      *(u16x4*)(rDb + (size_t)(b * SEQ + q0 + n * 16 + ln) * SEQ + kv0 + m * 16 + g * 4) = st;
    }
}

// ---------------- Kernel B: per-head flash PV, zero-LDS, all operands L2-direct ----------------
// Block: (b, head-pair hp, q64). Waves independent: (head = hp*2+(w>>1), q-half (w&1)*32).
__global__ __launch_bounds__(256, 4) void flashk(
    const unsigned short* __restrict__ Qp, const unsigned short* __restrict__ Kp,
    const unsigned short* __restrict__ Vt, const unsigned short* __restrict__ rDb,
    unsigned short* __restrict__ Ab) {
  const int tid = threadIdx.x, wave = tid >> 6, lane = tid & 63;
  const int g = lane >> 4, ln = lane & 15;
  const int o = blockIdx.x;                  // 1024 blocks
  const int l = (o & 7) * 128 + (o >> 3);    // XCD chunk covers one (b,hp) x all q-groups
  const int b = l >> 8;
  const int hp = (l >> 5) & 7;
  const int qg0 = (l & 31) * 64;
  const int hl = wave >> 1, h = hp * 2 + hl;
  const int qg = qg0 + (wave & 1) * 32;

  bf16x8 qf[2][2];
#pragma unroll
  for (int ks = 0; ks < 2; ++ks)
#pragma unroll
    for (int n = 0; n < 2; ++n)
      qf[ks][n] = *(const bf16x8*)(Qp + (size_t)(b * SEQ + qg + n * 16 + ln) * DMODEL + h * DKH + ks * 32 + g * 8);

  f32x4 ao[4][2] = {};
  const int a0 = ((g & 1) * 32 + ln) * 4;  // bpermute byte addr: src lane group (g&1)*2, same ln
  const int a1 = a0 + 64;                  // src lane group +1
  const bool gl = (g < 2);
  const size_t kbase = (size_t)(b * SEQ) * DMODEL + h * DKH;
  const size_t vbase = (size_t)((b * NH + h) * DKH) * SEQ;
  const size_t rbase0 = (size_t)(b * SEQ + qg + ln) * SEQ;

  for (int kv0 = 0; kv0 < SEQ; kv0 += 32) {
    // QK^T: S^T[kv32, q32] (bit-identical MFMA sequence to denomk)
    f32x4 s2[2][2] = {};
#pragma unroll
    for (int m = 0; m < 2; ++m) {
      const size_t kr = kbase + (size_t)(kv0 + m * 16 + ln) * DMODEL;
#pragma unroll
      for (int ks = 0; ks < 2; ++ks) {
        bf16x8 kf = *(const bf16x8*)(Kp + kr + ks * 32 + g * 8);
#pragma unroll
        for (int n = 0; n < 2; ++n)
          s2[m][n] = __builtin_amdgcn_mfma_f32_16x16x32_bf16(kf, qf[ks][n], s2[m][n], 0, 0, 0);
      }
    }
    // P = exp2(S*SEXP) * rD, pack bf16 (v_cvt_pk), transpose C-layout -> B-frag via bpermute
    bf16x8 pfr[2];
#pragma unroll
    for (int n = 0; n < 2; ++n) {
      uint32_t w[2][2];
#pragma unroll
      for (int m = 0; m < 2; ++m) {
        const size_t ra = rbase0 + (size_t)(n * 16) * SEQ + kv0 + m * 16 + g * 4;
        u16x4 rdq = *(const u16x4*)(rDb + ra);
        float p[4];
#pragma unroll
        for (int r = 0; r < 4; ++r) p[r] = exp2f(s2[m][n][r] * SEXP) * bf2f(rdq[r]);
        w[m][0] = cvtpk(p[0], p[1]);
        w[m][1] = cvtpk(p[2], p[3]);
      }
      uint32_t pr[4];
#pragma unroll
      for (int j2 = 0; j2 < 4; ++j2) {
        const int ad = (j2 & 2) ? a1 : a0;
        uint32_t b0 = (uint32_t)__builtin_amdgcn_ds_bpermute(ad, (int)w[0][j2 & 1]);
        uint32_t b1 = (uint32_t)__builtin_amdgcn_ds_bpermute(ad, (int)w[1][j2 & 1]);
        pr[j2] = gl ? b0 : b1;
      }
      union { uint32_t u[4]; bf16x8 v; } cvt;
      cvt.u[0] = pr[0]; cvt.u[1] = pr[1]; cvt.u[2] = pr[2]; cvt.u[3] = pr[3];
      pfr[n] = cvt.v;
    }
    // PV: ao^T[d64, q32] += V^T[d, kv32] * P^T[kv32, q32]
#pragma unroll
    for (int dt = 0; dt < 4; ++dt) {
      bf16x8 vf = *(const bf16x8*)(Vt + vbase + (size_t)(dt * 16 + ln) * SEQ + kv0 + g * 8);
#pragma unroll
      for (int n = 0; n < 2; ++n)
        ao[dt][n] = __builtin_amdgcn_mfma_f32_16x16x32_bf16(vf, pfr[n], ao[dt][n], 0, 0, 0);
    }
  }

#pragma unroll
  for (int dt = 0; dt < 4; ++dt)
#pragma unroll
    for (int n = 0; n < 2; ++n) {
      u16x4 st;
#pragma unroll
      for (int r = 0; r < 4; ++r) st[r] = f2bf(ao[dt][n][r]);
      *(u16x4*)(Ab + (size_t)(b * SEQ + qg + n * 16 + ln) * DMODEL + h * DKH + dt * 16 + g * 4) = st;
    }
}

extern "C" void kernel_launch(void* const* d_in, const int* in_sizes, int n_in,
                              void* d_out, int out_size, void* d_ws, size_t ws_size,
                              hipStream_t stream) {
  (void)in_sizes; (void)n_in; (void)out_size; (void)ws_size;
  const float* query = (const float*)d_in[0];
  const float* key   = (const float*)d_in[1];
  const float* value = (const float*)d_in[2];
  const float* Wq = (const float*)d_in[3];
  const float* bq = (const float*)d_in[4];
  const float* Wk = (const float*)d_in[5];
  const float* bk = (const float*)d_in[6];
  const float* Wv = (const float*)d_in[7];
  const float* bv = (const float*)d_in[8];
  const float* Wo = (const float*)d_in[9];
  const float* bo = (const float*)d_in[10];

  uint8_t* ws = (uint8_t*)d_ws;
  const size_t SZ = (size_t)4 * SEQ * DMODEL * 2;  // 16.78 MB per bf16 activation buffer
  // ws layout (67.1MB total, same footprint as round 1/2):
  //   ws0: Xv (bf16 value), later aliased by Qp   ws1: Kp   ws2: Vt   ws3: Ab
  unsigned short* Xv = (unsigned short*)(ws);
  unsigned short* Qp = (unsigned short*)(ws);          // alias: written after Xv consumed
  unsigned short* Kp = (unsigned short*)(ws + SZ);
  unsigned short* Vt = (unsigned short*)(ws + 2 * SZ);
  unsigned short* Ab = (unsigned short*)(ws + 3 * SZ);
  // d_out (33.55MB fp32) staging: Xq | Xk (bf16), both dead before denomk writes rD over all of it.
  unsigned short* Xq = (unsigned short*)d_out;
  unsigned short* Xk = (unsigned short*)d_out + (size_t)4 * SEQ * DMODEL / 2 * 2;  // +8.39M shorts
  unsigned short* rDb = (unsigned short*)d_out;

  cvtk<<<dim3(4096, 3), 256, 0, stream>>>(query, key, value, Xq, Xk, Xv);
  gemm2<1><<<512, 256, 0, stream>>>(Xv, Wv, bv, Vt);   // V first: frees ws0 for Qp
  gemm2<0><<<512, 256, 0, stream>>>(Xq, Wq, bq, Qp);
  gemm2<0><<<512, 256, 0, stream>>>(Xk, Wk, bk, Kp);
  denomk<<<2048, 256, 0, stream>>>(Qp, Kp, rDb);       // overwrites Xq/Xk with rD
  flashk<<<1024, 256, 0, stream>>>(Qp, Kp, Vt, rDb, Ab);
  gemm2<2><<<512, 256, 0, stream>>>(Ab, Wo, bo, (float*)d_out);  // overwrites rD
}

// Round 4
// 509.554 us; speedup vs baseline: 1.3469x; 1.3469x over previous
//
#include <hip/hip_runtime.h>
#include <stdint.h>

typedef __attribute__((ext_vector_type(8))) short bf16x8;
typedef __attribute__((ext_vector_type(4))) float f32x4;
typedef __attribute__((ext_vector_type(4))) float fl4;
typedef __attribute__((ext_vector_type(4))) unsigned short u16x4;
typedef __attribute__((ext_vector_type(8))) unsigned short u16x8;

constexpr int SEQ = 2048;
constexpr int DMODEL = 1024;
constexpr int NH = 16;
constexpr int DKH = 64;
constexpr float SEXP = 0.18033688f;  // log2(e)/8 — exp(s/8) == exp2(s*SEXP)

__device__ __forceinline__ unsigned short f2bf(float x) {
  union { float f; uint32_t u; } c;
  c.f = x;
  uint32_t u = c.u;
  u += 0x7FFFu + ((u >> 16) & 1u);
  return (unsigned short)(u >> 16);
}

__device__ __forceinline__ float bf2f(unsigned short u) {
  union { uint32_t u; float f; } c;
  c.u = ((uint32_t)u) << 16;
  return c.f;
}

__device__ __forceinline__ uint32_t cvtpk(float lo, float hi) {
  uint32_t r;
  asm("v_cvt_pk_bf16_f32 %0, %1, %2" : "=v"(r) : "v"(lo), "v"(hi));
  return r;
}

__device__ __forceinline__ int swz(int row) { return (row & 3) ^ ((row >> 2) & 3); }

__device__ __forceinline__ void gload16(const unsigned short* g, unsigned short* l) {
  __builtin_amdgcn_global_load_lds((const __attribute__((address_space(1))) void*)g,
                                   (__attribute__((address_space(3))) void*)l, 16, 0, 0);
}

// ---------------- fp32 -> bf16 conversions ----------------
__global__ __launch_bounds__(256) void cvtk(
    const float* __restrict__ s0, const float* __restrict__ s1, const float* __restrict__ s2,
    unsigned short* __restrict__ d0, unsigned short* __restrict__ d1, unsigned short* __restrict__ d2) {
  const float* s = blockIdx.y == 0 ? s0 : blockIdx.y == 1 ? s1 : s2;
  unsigned short* d = blockIdx.y == 0 ? d0 : blockIdx.y == 1 ? d1 : d2;
  const size_t i = ((size_t)blockIdx.x * 256 + threadIdx.x) * 8;
  fl4 a = *(const fl4*)(s + i);
  fl4 c = *(const fl4*)(s + i + 4);
  u16x8 r;
#pragma unroll
  for (int j = 0; j < 4; ++j) { r[j] = f2bf(a[j]); r[4 + j] = f2bf(c[j]); }
  *(u16x8*)(d + i) = r;
}

__global__ __launch_bounds__(256) void cvt1(
    const float* __restrict__ s, unsigned short* __restrict__ d) {
  const size_t i = ((size_t)blockIdx.x * 256 + threadIdx.x) * 8;
  fl4 a = *(const fl4*)(s + i);
  fl4 c = *(const fl4*)(s + i + 4);
  u16x8 r;
#pragma unroll
  for (int j = 0; j < 4; ++j) { r[j] = f2bf(a[j]); r[4 + j] = f2bf(c[j]); }
  *(u16x8*)(d + i) = r;
}

// ---------------- GEMM: C[8192,1024] = A_bf16 * B_bf16[1024,1024]^T + bias ----------------
// Both operands via global_load_lds (pre-swizzled source), 2-phase double-buffered pipeline.
// EPI: 0 = bf16 row-major; 1 = bf16 V^T [b][h][d][s]; 2 = fp32 row-major
template <int EPI>
__global__ __launch_bounds__(256, 2) void gemm3(
    const unsigned short* __restrict__ A, const unsigned short* __restrict__ Bb,
    const float* __restrict__ bias, void* __restrict__ Cp) {
  constexpr int K = DMODEL;
  constexpr int N = DMODEL;
  __shared__ unsigned short As[2][128 * 32];
  __shared__ unsigned short Bs[2][128 * 32];
  const int tid = threadIdx.x;
  const int wave = tid >> 6, lane = tid & 63;
  const int g = lane >> 4, ln = lane & 15;
  const int o = blockIdx.x;                 // 512 blocks, XCD-chunked
  const int l = (o & 7) * 64 + (o >> 3);
  const int r0 = (l & 63) * 128, c0 = (l >> 6) * 128;
  const int wr = (wave >> 1) * 64, wc = (wave & 1) * 64;

  f32x4 acc[4][4] = {};

  auto STAGE = [&](int buf, int kt) {
#pragma unroll
    for (int i = 0; i < 2; ++i) {
      const int row = i * 64 + (tid >> 2);
      const int cs = ((tid & 3) ^ swz(row)) * 8;
      gload16(A + (size_t)(r0 + row) * K + kt + cs, As[buf] + (i * 256 + wave * 64) * 8);
      gload16(Bb + (size_t)(c0 + row) * K + kt + cs, Bs[buf] + (i * 256 + wave * 64) * 8);
    }
  };

  STAGE(0, 0);
  __syncthreads();  // drains vmcnt before barrier

  for (int t = 0; t < K / 32; ++t) {
    const int buf = t & 1;
    if (t + 1 < K / 32) STAGE(buf ^ 1, (t + 1) * 32);
    bf16x8 af[4], bfr[4];
#pragma unroll
    for (int m = 0; m < 4; ++m) {
      const int row = wr + m * 16 + ln;
      af[m] = *(const bf16x8*)(As[buf] + row * 32 + ((g ^ swz(row)) * 8));
    }
#pragma unroll
    for (int n = 0; n < 4; ++n) {
      const int row = wc + n * 16 + ln;
      bfr[n] = *(const bf16x8*)(Bs[buf] + row * 32 + ((g ^ swz(row)) * 8));
    }
#pragma unroll
    for (int m = 0; m < 4; ++m)
#pragma unroll
      for (int n = 0; n < 4; ++n)
        acc[m][n] = __builtin_amdgcn_mfma_f32_16x16x32_bf16(af[m], bfr[n], acc[m][n], 0, 0, 0);
    __syncthreads();  // drains next-tile stage loads + syncs LDS reads
  }

  // epilogue: C/D layout col = lane&15, row = (lane>>4)*4 + reg
#pragma unroll
  for (int m = 0; m < 4; ++m) {
    const int row = r0 + wr + m * 16 + g * 4;
#pragma unroll
    for (int n = 0; n < 4; ++n) {
      const int col = c0 + wc + n * 16 + ln;
      const float bv = bias[col];
      f32x4 v = acc[m][n];
      if (EPI == 2) {
        float* C = (float*)Cp;
#pragma unroll
        for (int r = 0; r < 4; ++r) C[(size_t)(row + r) * N + col] = v[r] + bv;
      } else if (EPI == 0) {
        unsigned short* C = (unsigned short*)Cp;
#pragma unroll
        for (int r = 0; r < 4; ++r) C[(size_t)(row + r) * N + col] = f2bf(v[r] + bv);
      } else {
        unsigned short* Vt = (unsigned short*)Cp;
        const int bb = row >> 11, sl = row & 2047;
        const int h = col >> 6, d = col & 63;
        u16x4 pk;
#pragma unroll
        for (int r = 0; r < 4; ++r) pk[r] = f2bf(v[r] + bv);
        *(u16x4*)(Vt + ((size_t)((bb * NH + h) * DKH + d)) * SEQ + sl) = pk;
      }
    }
  }
}

// ---------------- Kernel A: head-softmax denominators ----------------
__global__ __launch_bounds__(256, 3) void denomk(
    const unsigned short* __restrict__ Qp, const unsigned short* __restrict__ Kp,
    unsigned short* __restrict__ rDb) {
  const int tid = threadIdx.x, wave = tid >> 6, lane = tid & 63;
  const int g = lane >> 4, ln = lane & 15;
  const int o = blockIdx.x;                  // 2048 blocks
  const int l = (o & 7) * 256 + (o >> 3);    // bijective XCD chunking
  const int b = l >> 9;
  const int qg = (l >> 4) & 31;
  const int kvg = l & 15;
  const int q0 = qg * 64, kv0 = kvg * 128 + wave * 32;

  f32x4 psum[2][4] = {};

  for (int h = 0; h < NH; ++h) {
    const int hb = h * DKH;
    bf16x8 qf[2][4];
#pragma unroll
    for (int ks = 0; ks < 2; ++ks)
#pragma unroll
      for (int n = 0; n < 4; ++n)
        qf[ks][n] = *(const bf16x8*)(Qp + (size_t)(b * SEQ + q0 + n * 16 + ln) * DMODEL + hb + ks * 32 + g * 8);
    bf16x8 kf[2][2];
#pragma unroll
    for (int m = 0; m < 2; ++m)
#pragma unroll
      for (int ks = 0; ks < 2; ++ks)
        kf[m][ks] = *(const bf16x8*)(Kp + (size_t)(b * SEQ + kv0 + m * 16 + ln) * DMODEL + hb + ks * 32 + g * 8);
    f32x4 s[2][4] = {};
#pragma unroll
    for (int m = 0; m < 2; ++m)
#pragma unroll
      for (int n = 0; n < 4; ++n) {
        s[m][n] = __builtin_amdgcn_mfma_f32_16x16x32_bf16(kf[m][0], qf[0][n], s[m][n], 0, 0, 0);
        s[m][n] = __builtin_amdgcn_mfma_f32_16x16x32_bf16(kf[m][1], qf[1][n], s[m][n], 0, 0, 0);
      }
#pragma unroll
    for (int m = 0; m < 2; ++m)
#pragma unroll
      for (int n = 0; n < 4; ++n)
#pragma unroll
        for (int r = 0; r < 4; ++r) psum[m][n][r] += exp2f(s[m][n][r] * SEXP);
  }

#pragma unroll
  for (int m = 0; m < 2; ++m)
#pragma unroll
    for (int n = 0; n < 4; ++n) {
      u16x4 st;
#pragma unroll
      for (int r = 0; r < 4; ++r) st[r] = f2bf(1.0f / psum[m][n][r]);
      *(u16x4*)(rDb + (size_t)(b * SEQ + q0 + n * 16 + ln) * SEQ + kv0 + m * 16 + g * 4) = st;
    }
}

// ---------------- Kernel B: per-head flash PV, LDS-staged K/V, 2-phase pipeline ----------------
// Block: (b, head-pair hp, q64). Waves: (head = hp*2+(w>>1), q-half (w&1)*32).
__global__ __launch_bounds__(256, 2) void flashk(
    const unsigned short* __restrict__ Qp, const unsigned short* __restrict__ Kp,
    const unsigned short* __restrict__ Vt, const unsigned short* __restrict__ rDb,
    unsigned short* __restrict__ Ab) {
  __shared__ unsigned short Ks[2][64 * 128];   // [kv64][dk128], chunk-swizzled
  __shared__ unsigned short Vs[2][128 * 64];   // [d128][kv64], chunk-swizzled
  const int tid = threadIdx.x, wave = tid >> 6, lane = tid & 63;
  const int g = lane >> 4, ln = lane & 15;
  const int o = blockIdx.x;                  // 1024 blocks
  const int l = (o & 7) * 128 + (o >> 3);    // XCD chunk covers one (b,hp) x all q-groups
  const int b = l >> 8;
  const int hp = (l >> 5) & 7;
  const int qg0 = (l & 31) * 64;
  const int hl = wave >> 1, h = hp * 2 + hl;
  const int qg = qg0 + (wave & 1) * 32;

  bf16x8 qf[2][2];
#pragma unroll
  for (int ks = 0; ks < 2; ++ks)
#pragma unroll
    for (int n = 0; n < 2; ++n)
      qf[ks][n] = *(const bf16x8*)(Qp + (size_t)(b * SEQ + qg + n * 16 + ln) * DMODEL + h * DKH + ks * 32 + g * 8);

  f32x4 ao[4][2] = {};
  const int a0 = ((g & 1) * 32 + ln) * 4;  // bpermute byte addr
  const int a1 = a0 + 64;
  const bool gl = (g < 2);
  const size_t rbase0 = (size_t)(b * SEQ + qg + ln) * SEQ;

  auto STAGE = [&](int buf, int kv0) {
#pragma unroll
    for (int i = 0; i < 4; ++i) {
      const int s = i * 256 + tid;
      {
        const int row = s >> 4, c = s & 15;
        const unsigned short* src =
            Kp + (size_t)(b * SEQ + kv0 + row) * DMODEL + hp * 128 + ((c ^ (row & 7)) * 8);
        gload16(src, Ks[buf] + (i * 256 + wave * 64) * 8);
      }
      {
        const int row = s >> 3, c = s & 7;
        const unsigned short* src =
            Vt + ((size_t)((b * NH + hp * 2 + (row >> 6)) * DKH + (row & 63))) * SEQ + kv0 + ((c ^ (row & 7)) * 8);
        gload16(src, Vs[buf] + (i * 256 + wave * 64) * 8);
      }
    }
  };

  STAGE(0, 0);
  __syncthreads();  // drains vmcnt

  for (int t = 0; t < SEQ / 64; ++t) {
    const int kv0 = t * 64;
    const int buf = t & 1;
    // rD prefetch for this tile FIRST (so its wait doesn't drain the stage loads)
    u16x4 rdq[2][2][2];  // [si][n][m]
#pragma unroll
    for (int si = 0; si < 2; ++si)
#pragma unroll
      for (int n = 0; n < 2; ++n)
#pragma unroll
        for (int m = 0; m < 2; ++m)
          rdq[si][n][m] = *(const u16x4*)(rDb + rbase0 + (size_t)(n * 16) * SEQ + kv0 + si * 32 + m * 16 + g * 4);
    if (t + 1 < SEQ / 64) STAGE(buf ^ 1, kv0 + 64);

#pragma unroll
    for (int si = 0; si < 2; ++si) {
      // QK^T: S^T[kv32, q32] (bit-identical MFMA sequence to denomk)
      f32x4 s2[2][2] = {};
#pragma unroll
      for (int m = 0; m < 2; ++m) {
        const int row = si * 32 + m * 16 + ln;
#pragma unroll
        for (int ks = 0; ks < 2; ++ks) {
          const int c = hl * 8 + ks * 4 + g;
          bf16x8 kf = *(const bf16x8*)(Ks[buf] + row * 128 + ((c ^ (row & 7)) * 8));
#pragma unroll
          for (int n = 0; n < 2; ++n)
            s2[m][n] = __builtin_amdgcn_mfma_f32_16x16x32_bf16(kf, qf[ks][n], s2[m][n], 0, 0, 0);
        }
      }
      // P = exp2(S*SEXP) * rD, pack bf16, transpose C-layout -> B-frag via bpermute
      bf16x8 pfr[2];
#pragma unroll
      for (int n = 0; n < 2; ++n) {
        uint32_t w[2][2];
#pragma unroll
        for (int m = 0; m < 2; ++m) {
          u16x4 rq = rdq[si][n][m];
          float p[4];
#pragma unroll
          for (int r = 0; r < 4; ++r) p[r] = exp2f(s2[m][n][r] * SEXP) * bf2f(rq[r]);
          w[m][0] = cvtpk(p[0], p[1]);
          w[m][1] = cvtpk(p[2], p[3]);
        }
        uint32_t pr[4];
#pragma unroll
        for (int j2 = 0; j2 < 4; ++j2) {
          const int ad = (j2 & 2) ? a1 : a0;
          uint32_t b0 = (uint32_t)__builtin_amdgcn_ds_bpermute(ad, (int)w[0][j2 & 1]);
          uint32_t b1 = (uint32_t)__builtin_amdgcn_ds_bpermute(ad, (int)w[1][j2 & 1]);
          pr[j2] = gl ? b0 : b1;
        }
        union { uint32_t u[4]; bf16x8 v; } cvt;
        cvt.u[0] = pr[0]; cvt.u[1] = pr[1]; cvt.u[2] = pr[2]; cvt.u[3] = pr[3];
        pfr[n] = cvt.v;
      }
      // PV: ao^T[d64, q32] += V^T[d, kv32] * P^T[kv32, q32]
#pragma unroll
      for (int dt = 0; dt < 4; ++dt) {
        const int vrow = hl * 64 + dt * 16 + ln;
        const int vc = si * 4 + g;
        bf16x8 vf = *(const bf16x8*)(Vs[buf] + vrow * 64 + ((vc ^ (vrow & 7)) * 8));
#pragma unroll
        for (int n = 0; n < 2; ++n)
          ao[dt][n] = __builtin_amdgcn_mfma_f32_16x16x32_bf16(vf, pfr[n], ao[dt][n], 0, 0, 0);
      }
    }
    __syncthreads();  // drains next-tile stage + syncs LDS reads
  }

#pragma unroll
  for (int dt = 0; dt < 4; ++dt)
#pragma unroll
    for (int n = 0; n < 2; ++n) {
      u16x4 st;
#pragma unroll
      for (int r = 0; r < 4; ++r) st[r] = f2bf(ao[dt][n][r]);
      *(u16x4*)(Ab + (size_t)(b * SEQ + qg + n * 16 + ln) * DMODEL + h * DKH + dt * 16 + g * 4) = st;
    }
}

extern "C" void kernel_launch(void* const* d_in, const int* in_sizes, int n_in,
                              void* d_out, int out_size, void* d_ws, size_t ws_size,
                              hipStream_t stream) {
  (void)in_sizes; (void)n_in; (void)out_size; (void)ws_size;
  const float* query = (const float*)d_in[0];
  const float* key   = (const float*)d_in[1];
  const float* value = (const float*)d_in[2];
  const float* Wq = (const float*)d_in[3];
  const float* bq = (const float*)d_in[4];
  const float* Wk = (const float*)d_in[5];
  const float* bk = (const float*)d_in[6];
  const float* Wv = (const float*)d_in[7];
  const float* bv = (const float*)d_in[8];
  const float* Wo = (const float*)d_in[9];
  const float* bo = (const float*)d_in[10];

  uint8_t* ws = (uint8_t*)d_ws;
  const size_t SZ = (size_t)4 * SEQ * DMODEL * 2;  // 16.78 MB per bf16 activation buffer
  const size_t WSZ = (size_t)DMODEL * DMODEL;      // 1M shorts per bf16 weight
  // ws layout (67.1MB, unchanged):
  unsigned short* Xv = (unsigned short*)(ws);
  unsigned short* Qp = (unsigned short*)(ws);              // alias: after Xv consumed
  unsigned short* Wob = (unsigned short*)(ws);             // alias: after Qp consumed (post-flashk)
  unsigned short* Kp = (unsigned short*)(ws + SZ);
  unsigned short* Vt = (unsigned short*)(ws + 2 * SZ);
  unsigned short* Ab = (unsigned short*)(ws + 3 * SZ);
  unsigned short* Wqb = Ab;                                // weights parked in Ab region
  unsigned short* Wkb = Ab + WSZ;                          // (dead until flashk overwrites,
  unsigned short* Wvb = Ab + 2 * WSZ;                      //  consumed before that)
  // d_out staging: Xq | Xk (bf16), later rD, finally the real output.
  unsigned short* Xq = (unsigned short*)d_out;
  unsigned short* Xk = (unsigned short*)d_out + (size_t)4 * SEQ * DMODEL;
  unsigned short* rDb = (unsigned short*)d_out;

  cvtk<<<dim3(4096, 3), 256, 0, stream>>>(query, key, value, Xq, Xk, Xv);
  cvt1<<<512, 256, 0, stream>>>(Wq, Wqb);
  cvt1<<<512, 256, 0, stream>>>(Wk, Wkb);
  cvt1<<<512, 256, 0, stream>>>(Wv, Wvb);
  gemm3<1><<<512, 256, 0, stream>>>(Xv, Wvb, bv, Vt);   // V first: frees ws0 for Qp
  gemm3<0><<<512, 256, 0, stream>>>(Xq, Wqb, bq, Qp);
  gemm3<0><<<512, 256, 0, stream>>>(Xk, Wkb, bk, Kp);
  denomk<<<2048, 256, 0, stream>>>(Qp, Kp, rDb);        // overwrites Xq/Xk with rD
  flashk<<<1024, 256, 0, stream>>>(Qp, Kp, Vt, rDb, Ab); // overwrites parked weights (dead)
  cvt1<<<512, 256, 0, stream>>>(Wo, Wob);               // Qp dead -> park Wo bf16 in ws0
  gemm3<2><<<512, 256, 0, stream>>>(Ab, Wob, bo, (float*)d_out);  // overwrites rD
}